// Round 4
// baseline (1380.806 us; speedup 1.0000x reference)
//
#include <hip/hip_runtime.h>

#define NNODES 100000
#define NMP 3
#define NEDGES 1000000
#define D 64
#define NTOT (NMP * NNODES)          // 300000
#define BN 128                       // destination nodes per bucket
#define NB ((NTOT + BN - 1) / BN)    // 2344 buckets
#define NSEG (NB * 8)                // 18752 (bucket x pseudo-xcd)
#define OVCAP 131072                 // overflow entries (12 B each)

typedef __attribute__((ext_vector_type(8))) short bf16x8;
typedef __attribute__((ext_vector_type(4))) float floatx4;

__device__ __forceinline__ unsigned short f2bf(float f) {
    unsigned u = __float_as_uint(f);
    u = (u + 0x7FFFu + ((u >> 16) & 1u)) >> 16;   // RNE
    return (unsigned short)u;
}
__device__ __forceinline__ float bf2f_lo(unsigned u) { return __uint_as_float(u << 16); }
__device__ __forceinline__ float bf2f_hi(unsigned u) { return __uint_as_float(u & 0xFFFF0000u); }

// ---------------- place: append {clocal|rflat, ew} to (bucket, pseudo-xcd) segment ----------------
__global__ __launch_bounds__(256) void place_kernel(const int* __restrict__ ei,
                                                    const float* __restrict__ ew,
                                                    int* __restrict__ cursors,
                                                    int* __restrict__ ovcur,
                                                    int* __restrict__ ovf,
                                                    uint2* __restrict__ pairs, int cap) {
    int e = blockIdx.x * 256 + threadIdx.x;
    int mp = blockIdx.y;
    if (e >= NEDGES) return;
    int r = ei[(mp * 2 + 0) * NEDGES + e];
    int c = ei[(mp * 2 + 1) * NEDGES + e];
    float w = ew[mp * NEDGES + e];
    int rflat = mp * NNODES + r;
    int cflat = mp * NNODES + c;
    int bucket = cflat >> 7;
    int clocal = cflat & 127;
    // consecutive blocks round-robin over XCDs -> same (id&7) shares an L2 (perf-only heuristic)
    int px = (blockIdx.y * gridDim.x + blockIdx.x) & 7;
    int seg = bucket * 8 + px;
    int pos = atomicAdd(&cursors[seg], 1);
    if (pos < cap) {
        pairs[(size_t)seg * cap + pos] =
            make_uint2(((unsigned)clocal << 19) | (unsigned)rflat, __float_as_uint(w));
    } else {                                     // correctness valve; statistically ~empty
        int op = atomicAdd(ovcur, 1);
        if (op < OVCAP) {
            ovf[3 * op] = cflat; ovf[3 * op + 1] = rflat; ovf[3 * op + 2] = __float_as_int(w);
        }
    }
}

// ---------------- dinv: per-bucket LDS sum of ew -> rsqrt (replaces global-atomic deg pass) ----------------
__global__ __launch_bounds__(256) void dinv_kernel(const int* __restrict__ cursors,
                                                   const uint2* __restrict__ pairs,
                                                   const int* __restrict__ ovcur,
                                                   const int* __restrict__ ovf,
                                                   float* __restrict__ dinv, int cap) {
    int bucket = blockIdx.x;
    __shared__ float ds[BN];
    int tid = threadIdx.x;
    if (tid < BN) ds[tid] = 0.0f;
    __syncthreads();
    for (int s = 0; s < 8; ++s) {
        int seg = bucket * 8 + s;
        int len = min(cursors[seg], cap);
        const uint2* sp = pairs + (size_t)seg * cap;
        for (int p = tid; p < len; p += 256) {
            uint2 pr = sp[p];
            atomicAdd(&ds[pr.x >> 19], __uint_as_float(pr.y));
        }
    }
    int ovn = min(*ovcur, OVCAP);
    for (int i = tid; i < ovn; i += 256) {
        int cflat = ovf[3 * i];
        if ((cflat >> 7) == bucket) atomicAdd(&ds[cflat & 127], __int_as_float(ovf[3 * i + 2]));
    }
    __syncthreads();
    if (tid < BN) {
        int node = bucket * BN + tid;
        if (node < NTOT) {
            float d = ds[tid];
            dinv[node] = (d > 0.0f) ? rsqrtf(d) : 0.0f;
        }
    }
}

// ---------------- prep: W fp32 [mp][k][n] -> bf16 transposed wT [mp][n][k] ----------------
__global__ __launch_bounds__(256) void prep_w_kernel(const float* __restrict__ W,
                                                     unsigned short* __restrict__ wT) {
    int idx = blockIdx.x * 256 + threadIdx.x;
    if (idx >= NMP * D * D) return;
    int mp = idx >> 12, rem = idx & 4095;
    int k = rem >> 6, n = rem & 63;
    wT[(mp * D + n) * D + k] = f2bf(W[idx]);
}

// ---------------- MFMA GEMM: h'[mp][r] = bf16( (x @ W[mp])[r] * dinv[mp,r] ) ----------------
__global__ __launch_bounds__(256) void gemm_kernel(const float* __restrict__ x,
                                                   const unsigned short* __restrict__ wT,
                                                   const float* __restrict__ dinv,
                                                   unsigned short* __restrict__ h) {
    const int wave = threadIdx.x >> 6;
    const int lane = threadIdx.x & 63;
    const int rowbase = (blockIdx.x * 4 + wave) * 16;
    if (rowbase >= NNODES) return;
    const int m = lane & 15;
    const int q = lane >> 4;
    const float4* xr = (const float4*)(x + (size_t)(rowbase + m) * D);
    bf16x8 a[2];
#pragma unroll
    for (int kc = 0; kc < 2; ++kc) {
        float4 x0 = xr[kc * 8 + q * 2];
        float4 x1 = xr[kc * 8 + q * 2 + 1];
        a[kc][0] = f2bf(x0.x); a[kc][1] = f2bf(x0.y);
        a[kc][2] = f2bf(x0.z); a[kc][3] = f2bf(x0.w);
        a[kc][4] = f2bf(x1.x); a[kc][5] = f2bf(x1.y);
        a[kc][6] = f2bf(x1.z); a[kc][7] = f2bf(x1.w);
    }
#pragma unroll
    for (int mp = 0; mp < NMP; ++mp) {
        float dv[4];
#pragma unroll
        for (int r_ = 0; r_ < 4; ++r_)
            dv[r_] = dinv[mp * NNODES + rowbase + q * 4 + r_];
#pragma unroll
        for (int nt = 0; nt < 4; ++nt) {
            int ncol = nt * 16 + m;
            const bf16x8* bp = (const bf16x8*)(wT + (size_t)(mp * D + ncol) * D);
            bf16x8 b0 = bp[q];
            bf16x8 b1 = bp[4 + q];
            floatx4 acc = {0.f, 0.f, 0.f, 0.f};
            acc = __builtin_amdgcn_mfma_f32_16x16x32_bf16(a[0], b0, acc, 0, 0, 0);
            acc = __builtin_amdgcn_mfma_f32_16x16x32_bf16(a[1], b1, acc, 0, 0, 0);
            unsigned short* hp = h + ((size_t)mp * NNODES + rowbase) * D + ncol;
#pragma unroll
            for (int r_ = 0; r_ < 4; ++r_)
                hp[(q * 4 + r_) * D] = f2bf(acc[r_] * dv[r_]);   // C/D: col=lane&15, row=q*4+r
        }
    }
}

// ---------------- gather: block per bucket; LDS fp32 tile accumulate; dense out writes ----------------
__global__ __launch_bounds__(256) void gather_kernel(const int* __restrict__ cursors,
                                                     const uint2* __restrict__ pairs,
                                                     const int* __restrict__ ovcur,
                                                     const int* __restrict__ ovf,
                                                     const unsigned short* __restrict__ h,
                                                     const float* __restrict__ dinv,
                                                     float* __restrict__ out, int cap) {
    int bucket = blockIdx.x;
    __shared__ float tile[BN * 65];       // +1 dword pad per row: bank-staggered
    int tid = threadIdx.x;
    float4* t4 = (float4*)tile;
    for (int i = tid; i < BN * 65 / 4; i += 256) t4[i] = make_float4(0.f, 0.f, 0.f, 0.f);
    __syncthreads();
    int wave = tid >> 6, lane = tid & 63;
    int g = lane & 7;      // pair slot within 8-wide group
    int f = lane >> 3;     // feature chunk (8 bf16 = 16 B)
    for (int s = 0; s < 2; ++s) {
        int seg = bucket * 8 + wave + s * 4;
        int len = min(cursors[seg], cap);
        const uint2* sp = pairs + (size_t)seg * cap;
        for (int p0 = 0; p0 < len; p0 += 8) {
            int idx = p0 + g;
            uint2 pr = (idx < len) ? sp[idx] : make_uint2(0u, 0u);   // ew=0 -> no-op
            unsigned rflat = pr.x & 0x7FFFFu;
            int cl = pr.x >> 19;
            float ewv = __uint_as_float(pr.y);
            const uint4* hp = (const uint4*)(h + (size_t)rflat * D);
            uint4 hv = hp[f];
            float* dst = tile + cl * 65 + f * 8;
            atomicAdd(dst + 0, ewv * bf2f_lo(hv.x));
            atomicAdd(dst + 1, ewv * bf2f_hi(hv.x));
            atomicAdd(dst + 2, ewv * bf2f_lo(hv.y));
            atomicAdd(dst + 3, ewv * bf2f_hi(hv.y));
            atomicAdd(dst + 4, ewv * bf2f_lo(hv.z));
            atomicAdd(dst + 5, ewv * bf2f_hi(hv.z));
            atomicAdd(dst + 6, ewv * bf2f_lo(hv.w));
            atomicAdd(dst + 7, ewv * bf2f_hi(hv.w));
        }
    }
    int ovn = min(*ovcur, OVCAP);
    for (int i = tid; i < ovn; i += 256) {       // rare correctness path
        int cflat = ovf[3 * i];
        if ((cflat >> 7) == bucket) {
            int cl = cflat & 127;
            unsigned rf = (unsigned)ovf[3 * i + 1];
            float ewv = __int_as_float(ovf[3 * i + 2]);
            for (int j = 0; j < D; ++j) {
                float hval = __uint_as_float(((unsigned)h[(size_t)rf * D + j]) << 16);
                atomicAdd(&tile[cl * 65 + j], ewv * hval);
            }
        }
    }
    __syncthreads();
#pragma unroll 4
    for (int it = 0; it < BN / 4; ++it) {
        int row = it * 4 + wave;
        int node = bucket * BN + row;
        if (node < NTOT) {
            float v = tile[row * 65 + lane] * dinv[node];
            out[(size_t)node * D + lane] = fmaxf(v, 0.0f);
        }
    }
}

extern "C" void kernel_launch(void* const* d_in, const int* in_sizes, int n_in,
                              void* d_out, int out_size, void* d_ws, size_t ws_size,
                              hipStream_t stream) {
    const float* x  = (const float*)d_in[0];   // [N, 64]
    const float* W  = (const float*)d_in[1];   // [3, 64, 64]
    const int*   ei = (const int*)d_in[2];     // [3, 2, E]
    const float* ew = (const float*)d_in[3];   // [3, E]
    float* out = (float*)d_out;                // [3, N, 64]

    char* ws = (char*)d_ws;
    unsigned short* h  = (unsigned short*)(ws + 0);            // 38,400,000 B
    float* dinv        = (float*)(ws + 38400000);              // 1,200,000 B
    unsigned short* wT = (unsigned short*)(ws + 39600000);     // 24,576 B
    int*   cursors     = (int*)(ws + 39624576);                // 75,008 B
    int*   ovcur       = (int*)(ws + 39699584);                // 4 B (+pad to 64)
    int*   ovf         = (int*)(ws + 39699648);                // 1,572,864 B
    uint2* pairs       = (uint2*)(ws + 41272512);              // NSEG * cap * 8 B

    int cap = (int)((ws_size - 41272512) / ((size_t)NSEG * 8));
    cap &= ~7;                                   // 64B-aligned segments
    if (cap > 640) cap = 640;

    hipMemsetAsync(cursors, 0, 75072, stream);   // cursors + ovcur

    dim3 egrid((NEDGES + 255) / 256, NMP);
    place_kernel<<<egrid, 256, 0, stream>>>(ei, ew, cursors, ovcur, ovf, pairs, cap);
    dinv_kernel<<<NB, 256, 0, stream>>>(cursors, pairs, ovcur, ovf, dinv, cap);
    prep_w_kernel<<<(NMP * D * D + 255) / 256, 256, 0, stream>>>(W, wT);
    gemm_kernel<<<(NNODES / 16 + 3) / 4, 256, 0, stream>>>(x, wT, dinv, h);
    gather_kernel<<<NB, 256, 0, stream>>>(cursors, pairs, ovcur, ovf, h, dinv, out, cap);
}

// Round 5
// 481.531 us; speedup vs baseline: 2.8675x; 2.8675x over previous
//
#include <hip/hip_runtime.h>

#define NNODES 100000
#define NMP 3
#define NEDGES 1000000
#define D 64
#define NTOT (NMP * NNODES)          // 300000
#define BN 128                       // destination nodes per bucket
#define NB ((NTOT + BN - 1) / BN)    // 2344 buckets
#define NSEG (NB * 8)                // 18752 (bucket x pseudo-xcd)
#define CAP 240                      // slots per segment (lambda=160, +6.3 sigma)
#define OVCAP 131072                 // overflow entries (12 B each)

typedef __attribute__((ext_vector_type(8))) short bf16x8;
typedef __attribute__((ext_vector_type(4))) float floatx4;

__device__ __forceinline__ unsigned short f2bf(float f) {
    unsigned u = __float_as_uint(f);
    u = (u + 0x7FFFu + ((u >> 16) & 1u)) >> 16;   // RNE
    return (unsigned short)u;
}
__device__ __forceinline__ float bf2f_lo(unsigned u) { return __uint_as_float(u << 16); }
__device__ __forceinline__ float bf2f_hi(unsigned u) { return __uint_as_float(u & 0xFFFF0000u); }

// ---------------- place: append {clocal|rflat, ew} to (bucket, pseudo-xcd) segment ----------------
__global__ __launch_bounds__(256) void place_kernel(const int* __restrict__ ei,
                                                    const float* __restrict__ ew,
                                                    int* __restrict__ cursors,
                                                    int* __restrict__ ovcur,
                                                    int* __restrict__ ovf,
                                                    uint2* __restrict__ pairs) {
    int e = blockIdx.x * 256 + threadIdx.x;
    int mp = blockIdx.y;
    if (e >= NEDGES) return;
    int r = ei[(mp * 2 + 0) * NEDGES + e];
    int c = ei[(mp * 2 + 1) * NEDGES + e];
    float w = ew[mp * NEDGES + e];
    int rflat = mp * NNODES + r;
    int cflat = mp * NNODES + c;
    int bucket = cflat >> 7;
    int clocal = cflat & 127;
    // consecutive blocks round-robin over XCDs -> same (id&7) shares an L2 (perf heuristic only)
    int px = (blockIdx.y * gridDim.x + blockIdx.x) & 7;
    int seg = bucket * 8 + px;
    int pos = atomicAdd(&cursors[seg], 1);
    if (pos < CAP) {
        pairs[(size_t)seg * CAP + pos] =
            make_uint2(((unsigned)clocal << 19) | (unsigned)rflat, __float_as_uint(w));
    } else {                                     // correctness valve; statistically empty
        int op = atomicAdd(ovcur, 1);
        if (op < OVCAP) {
            ovf[3 * op] = cflat; ovf[3 * op + 1] = rflat; ovf[3 * op + 2] = __float_as_int(w);
        }
    }
}

// ---------------- bscan: exclusive scan of per-bucket totals (1 block) ----------------
__global__ __launch_bounds__(256) void bscan_kernel(const int* __restrict__ cursors,
                                                    const int* __restrict__ ovcur,
                                                    const int* __restrict__ ovf,
                                                    int* __restrict__ bstart) {
    __shared__ int btot[NB];          // 9376 B
    __shared__ int sh[256];
    __shared__ int carry;
    int t = threadIdx.x;
    for (int b = t; b < NB; b += 256) {
        int tot = 0;
#pragma unroll
        for (int s = 0; s < 8; ++s) tot += min(cursors[b * 8 + s], CAP);
        btot[b] = tot;
    }
    __syncthreads();
    int ovn = min(*ovcur, OVCAP);
    for (int i = t; i < ovn; i += 256) atomicAdd(&btot[ovf[3 * i] >> 7], 1);
    if (t == 0) carry = 0;
    __syncthreads();
    for (int base = 0; base < NB; base += 256) {
        int idx = base + t;
        int v = (idx < NB) ? btot[idx] : 0;
        sh[t] = v;
        __syncthreads();
        for (int d = 1; d < 256; d <<= 1) {
            int add = (t >= d) ? sh[t - d] : 0;
            __syncthreads();
            sh[t] += add;
            __syncthreads();
        }
        if (idx < NB) bstart[idx] = carry + sh[t] - v;
        __syncthreads();
        if (t == 0) carry += sh[255];
        __syncthreads();
    }
}

// ---------------- compact: per bucket -> per-node dense CSR {rflat, ew}; also dinv ----------------
__global__ __launch_bounds__(256) void compact_kernel(const int* __restrict__ cursors,
                                                      const uint2* __restrict__ seg,
                                                      const int* __restrict__ ovcur,
                                                      const int* __restrict__ ovf,
                                                      const int* __restrict__ bstart,
                                                      uint2* __restrict__ dense,
                                                      int2* __restrict__ nodeoff,
                                                      float* __restrict__ dinv) {
    int bucket = blockIdx.x;
    __shared__ int cnt[BN];
    __shared__ float wsum[BN];
    __shared__ int excl[BN];
    __shared__ int cur[BN];
    int t = threadIdx.x;
    if (t < BN) { cnt[t] = 0; wsum[t] = 0.0f; }
    __syncthreads();
    int ovn = min(*ovcur, OVCAP);
    // phase 1: per-node counts + weighted degree
    for (int s = 0; s < 8; ++s) {
        int len = min(cursors[bucket * 8 + s], CAP);
        const uint2* sp = seg + (size_t)(bucket * 8 + s) * CAP;
        for (int p = t; p < len; p += 256) {
            uint2 pr = sp[p];
            int cl = pr.x >> 19;
            atomicAdd(&cnt[cl], 1);
            atomicAdd(&wsum[cl], __uint_as_float(pr.y));
        }
    }
    for (int i = t; i < ovn; i += 256) {
        int cflat = ovf[3 * i];
        if ((cflat >> 7) == bucket) {
            atomicAdd(&cnt[cflat & 127], 1);
            atomicAdd(&wsum[cflat & 127], __int_as_float(ovf[3 * i + 2]));
        }
    }
    __syncthreads();
    // scan cnt -> inclusive in excl
    if (t < BN) excl[t] = cnt[t];
    __syncthreads();
    for (int d = 1; d < BN; d <<= 1) {
        int v = (t < BN && t >= d) ? excl[t - d] : 0;
        __syncthreads();
        if (t < BN) excl[t] += v;
        __syncthreads();
    }
    int base = bstart[bucket];
    if (t < BN) {
        int start = base + excl[t] - cnt[t];
        cur[t] = start;
        int node = bucket * BN + t;
        if (node < NTOT) {
            nodeoff[node] = make_int2(start, cnt[t]);
            float dg = wsum[t];
            dinv[node] = (dg > 0.0f) ? rsqrtf(dg) : 0.0f;
        }
    }
    __syncthreads();
    // phase 2: scatter into dense (writes land in a ~10KB hot region -> L2 merges lines)
    for (int s = 0; s < 8; ++s) {
        int len = min(cursors[bucket * 8 + s], CAP);
        const uint2* sp = seg + (size_t)(bucket * 8 + s) * CAP;
        for (int p = t; p < len; p += 256) {
            uint2 pr = sp[p];
            int cl = pr.x >> 19;
            int pos = atomicAdd(&cur[cl], 1);
            dense[pos] = make_uint2(pr.x & 0x7FFFFu, pr.y);
        }
    }
    for (int i = t; i < ovn; i += 256) {
        int cflat = ovf[3 * i];
        if ((cflat >> 7) == bucket) {
            int pos = atomicAdd(&cur[cflat & 127], 1);
            dense[pos] = make_uint2((unsigned)ovf[3 * i + 1], (unsigned)ovf[3 * i + 2]);
        }
    }
}

// ---------------- prep: W fp32 [mp][k][n] -> bf16 transposed wT [mp][n][k] ----------------
__global__ __launch_bounds__(256) void prep_w_kernel(const float* __restrict__ W,
                                                     unsigned short* __restrict__ wT) {
    int idx = blockIdx.x * 256 + threadIdx.x;
    if (idx >= NMP * D * D) return;
    int mp = idx >> 12, rem = idx & 4095;
    int k = rem >> 6, n = rem & 63;
    wT[(mp * D + n) * D + k] = f2bf(W[idx]);
}

// ---------------- MFMA GEMM: h'[mp][r] = bf16( (x @ W[mp])[r] * dinv[mp,r] ) ----------------
__global__ __launch_bounds__(256) void gemm_kernel(const float* __restrict__ x,
                                                   const unsigned short* __restrict__ wT,
                                                   const float* __restrict__ dinv,
                                                   unsigned short* __restrict__ h) {
    const int wave = threadIdx.x >> 6;
    const int lane = threadIdx.x & 63;
    const int rowbase = (blockIdx.x * 4 + wave) * 16;
    if (rowbase >= NNODES) return;
    const int m = lane & 15;
    const int q = lane >> 4;
    const float4* xr = (const float4*)(x + (size_t)(rowbase + m) * D);
    bf16x8 a[2];
#pragma unroll
    for (int kc = 0; kc < 2; ++kc) {
        float4 x0 = xr[kc * 8 + q * 2];
        float4 x1 = xr[kc * 8 + q * 2 + 1];
        a[kc][0] = f2bf(x0.x); a[kc][1] = f2bf(x0.y);
        a[kc][2] = f2bf(x0.z); a[kc][3] = f2bf(x0.w);
        a[kc][4] = f2bf(x1.x); a[kc][5] = f2bf(x1.y);
        a[kc][6] = f2bf(x1.z); a[kc][7] = f2bf(x1.w);
    }
#pragma unroll
    for (int mp = 0; mp < NMP; ++mp) {
        float dv[4];
#pragma unroll
        for (int r_ = 0; r_ < 4; ++r_)
            dv[r_] = dinv[mp * NNODES + rowbase + q * 4 + r_];
#pragma unroll
        for (int nt = 0; nt < 4; ++nt) {
            int ncol = nt * 16 + m;
            const bf16x8* bp = (const bf16x8*)(wT + (size_t)(mp * D + ncol) * D);
            bf16x8 b0 = bp[q];
            bf16x8 b1 = bp[4 + q];
            floatx4 acc = {0.f, 0.f, 0.f, 0.f};
            acc = __builtin_amdgcn_mfma_f32_16x16x32_bf16(a[0], b0, acc, 0, 0, 0);
            acc = __builtin_amdgcn_mfma_f32_16x16x32_bf16(a[1], b1, acc, 0, 0, 0);
            unsigned short* hp = h + ((size_t)mp * NNODES + rowbase) * D + ncol;
#pragma unroll
            for (int r_ = 0; r_ < 4; ++r_)
                hp[(q * 4 + r_) * D] = f2bf(acc[r_] * dv[r_]);   // C/D: col=lane&15, row=q*4+r
        }
    }
}

// ---------------- gather: wave per node, register accumulation, 16 pairs in flight ----------------
__global__ __launch_bounds__(256) void gather_kernel(const int2* __restrict__ nodeoff,
                                                     const uint2* __restrict__ dense,
                                                     const unsigned short* __restrict__ h,
                                                     const float* __restrict__ dinv,
                                                     float* __restrict__ out) {
    int w = blockIdx.x * 4 + (threadIdx.x >> 6);
    if (w >= NTOT) return;
    int lane = threadIdx.x & 63;
    int g = lane & 7;    // pair slot within group
    int f = lane >> 3;   // feature chunk (8 bf16 = 16 B)
    int2 off = nodeoff[w];
    int start = off.x, end = off.x + off.y;
    float acc[8] = {0, 0, 0, 0, 0, 0, 0, 0};
    for (int p = start; p < end; p += 16) {
        int i0 = p + g;
        int i1 = p + 8 + g;
        uint2 pr0 = (i0 < end) ? dense[i0] : make_uint2(0u, 0u);   // ew=0 -> no-op
        uint2 pr1 = (i1 < end) ? dense[i1] : make_uint2(0u, 0u);
        uint4 hv0 = ((const uint4*)(h + (size_t)pr0.x * D))[f];
        uint4 hv1 = ((const uint4*)(h + (size_t)pr1.x * D))[f];
        float n0 = __uint_as_float(pr0.y);
        float n1 = __uint_as_float(pr1.y);
        acc[0] += n0 * bf2f_lo(hv0.x); acc[1] += n0 * bf2f_hi(hv0.x);
        acc[2] += n0 * bf2f_lo(hv0.y); acc[3] += n0 * bf2f_hi(hv0.y);
        acc[4] += n0 * bf2f_lo(hv0.z); acc[5] += n0 * bf2f_hi(hv0.z);
        acc[6] += n0 * bf2f_lo(hv0.w); acc[7] += n0 * bf2f_hi(hv0.w);
        acc[0] += n1 * bf2f_lo(hv1.x); acc[1] += n1 * bf2f_hi(hv1.x);
        acc[2] += n1 * bf2f_lo(hv1.y); acc[3] += n1 * bf2f_hi(hv1.y);
        acc[4] += n1 * bf2f_lo(hv1.z); acc[5] += n1 * bf2f_hi(hv1.z);
        acc[6] += n1 * bf2f_lo(hv1.w); acc[7] += n1 * bf2f_hi(hv1.w);
    }
#pragma unroll
    for (int j = 0; j < 8; ++j) {
        acc[j] += __shfl_xor(acc[j], 1);
        acc[j] += __shfl_xor(acc[j], 2);
        acc[j] += __shfl_xor(acc[j], 4);
    }
    int k = lane & 7;   // lane l holds feature (l>>3)*8 + j in acc[j]; wants acc[l&7]
    float b0 = (k & 1) ? acc[1] : acc[0];
    float b1 = (k & 1) ? acc[3] : acc[2];
    float b2 = (k & 1) ? acc[5] : acc[4];
    float b3 = (k & 1) ? acc[7] : acc[6];
    float c0 = (k & 2) ? b1 : b0;
    float c1 = (k & 2) ? b3 : b2;
    float v  = (k & 4) ? c1 : c0;
    out[(size_t)w * D + lane] = fmaxf(v * dinv[w], 0.0f);
}

extern "C" void kernel_launch(void* const* d_in, const int* in_sizes, int n_in,
                              void* d_out, int out_size, void* d_ws, size_t ws_size,
                              hipStream_t stream) {
    const float* x  = (const float*)d_in[0];   // [N, 64]
    const float* W  = (const float*)d_in[1];   // [3, 64, 64]
    const int*   ei = (const int*)d_in[2];     // [3, 2, E]
    const float* ew = (const float*)d_in[3];   // [3, E]
    float* out = (float*)d_out;                // [3, N, 64]

    // layout (bytes): region A (38.4 MB) holds seg-pairs first, then h (seg dead before gemm)
    char* ws = (char*)d_ws;
    uint2* segp        = (uint2*)(ws + 0);                     // 18752*240*8 = 36,003,840 B
    unsigned short* h  = (unsigned short*)(ws + 0);            // 38,400,000 B (overlays segp)
    uint2* dense       = (uint2*)(ws + 38400000);              // 24,000,000 B
    int2*  nodeoff     = (int2*)(ws + 62400000);               // 2,400,000 B
    float* dinv        = (float*)(ws + 64800000);              // 1,200,000 B
    unsigned short* wT = (unsigned short*)(ws + 66000000);     // 24,576 B
    int*   cursors     = (int*)(ws + 66024576);                // 75,008 B
    int*   ovcur       = (int*)(ws + 66099584);                // 64 B
    int*   ovf         = (int*)(ws + 66099648);                // 1,572,864 B
    int*   bstart      = (int*)(ws + 67672512);                // 9,376 B

    hipMemsetAsync(cursors, 0, 75072, stream);   // cursors + ovcur

    dim3 egrid((NEDGES + 255) / 256, NMP);
    place_kernel<<<egrid, 256, 0, stream>>>(ei, ew, cursors, ovcur, ovf, segp);
    bscan_kernel<<<1, 256, 0, stream>>>(cursors, ovcur, ovf, bstart);
    compact_kernel<<<NB, 256, 0, stream>>>(cursors, segp, ovcur, ovf, bstart,
                                           dense, nodeoff, dinv);
    prep_w_kernel<<<(NMP * D * D + 255) / 256, 256, 0, stream>>>(W, wT);
    gemm_kernel<<<(NNODES / 16 + 3) / 4, 256, 0, stream>>>(x, wT, dinv, h);
    gather_kernel<<<(NTOT + 3) / 4, 256, 0, stream>>>(nodeoff, dense, h, dinv, out);
}

// Round 6
// 317.503 us; speedup vs baseline: 4.3490x; 1.5166x over previous
//
#include <hip/hip_runtime.h>

#define NNODES 100000
#define NMP 3
#define NEDGES 1000000
#define D 64
#define NTOT (NMP * NNODES)          // 300000
#define BINW 1024                    // destination nodes per bin
#define NBIN 293                     // ceil(NTOT / BINW)
#define CAPB 10944                   // slots per bin segment (lambda=10240, +7 sigma)
#define T1 3072                      // edges per split block
#define OVCAP 131072                 // overflow entries (12 B each)

typedef __attribute__((ext_vector_type(8))) short bf16x8;
typedef __attribute__((ext_vector_type(4))) float floatx4;

__device__ __forceinline__ unsigned short f2bf(float f) {
    unsigned u = __float_as_uint(f);
    u = (u + 0x7FFFu + ((u >> 16) & 1u)) >> 16;   // RNE
    return (unsigned short)u;
}
__device__ __forceinline__ float bf2f_lo(unsigned u) { return __uint_as_float(u << 16); }
__device__ __forceinline__ float bf2f_hi(unsigned u) { return __uint_as_float(u & 0xFFFF0000u); }

// ---------------- split: LDS-staged multisplit of edges into 293 bins ----------------
// Record: key = (cflat&1023)<<19 | rflat, payload = ew. Writes are bin-sorted runs.
__global__ __launch_bounds__(512) void split_kernel(const int* __restrict__ ei,
                                                    const float* __restrict__ ew,
                                                    int* __restrict__ gcur,
                                                    int* __restrict__ ovcur,
                                                    int* __restrict__ ovf,
                                                    uint2* __restrict__ A) {
    __shared__ int hist[NBIN], binstart[NBIN], cur[NBIN], gb[NBIN];
    __shared__ int sA[512], sB[512];
    __shared__ uint2 tile[T1];
    __shared__ unsigned short tbin[T1];
    __shared__ int stotal;
    const int t = threadIdx.x;
    const int mp = blockIdx.y;
    const int e0 = blockIdx.x * T1;
    for (int i = t; i < NBIN; i += 512) { hist[i] = 0; cur[i] = 0; }
    __syncthreads();
    unsigned key[6]; float w[6]; int bn[6];
#pragma unroll
    for (int i = 0; i < 6; ++i) {
        int e = e0 + i * 512 + t;
        bn[i] = -1;
        if (e < NEDGES) {
            int r = ei[(mp * 2 + 0) * NEDGES + e];
            int c = ei[(mp * 2 + 1) * NEDGES + e];
            w[i] = ew[mp * NEDGES + e];
            int cflat = mp * NNODES + c;
            int rflat = mp * NNODES + r;
            int b = cflat >> 10;
            bn[i] = b;
            key[i] = ((unsigned)(cflat & 1023) << 19) | (unsigned)rflat;
            atomicAdd(&hist[b], 1);                     // LDS atomic
        }
    }
    __syncthreads();
    // inclusive scan of hist (padded to 512) -> binstart (exclusive), stotal
    int v = (t < NBIN) ? hist[t] : 0;
    sA[t] = v;
    __syncthreads();
    int* src = sA; int* dst = sB;
    for (int d = 1; d < 512; d <<= 1) {
        dst[t] = src[t] + ((t >= d) ? src[t - d] : 0);
        __syncthreads();
        int* tmp = src; src = dst; dst = tmp;
    }
    if (t < NBIN) {
        binstart[t] = src[t] - v;
        gb[t] = v ? atomicAdd(&gcur[t], v) : 0;         // global space reservation
    }
    if (t == 511) stotal = src[511];
    __syncthreads();
    // rank + reorder into LDS (bin-sorted)
#pragma unroll
    for (int i = 0; i < 6; ++i) {
        if (bn[i] >= 0) {
            int rk = atomicAdd(&cur[bn[i]], 1);
            int s = binstart[bn[i]] + rk;
            tile[s] = make_uint2(key[i], __float_as_uint(w[i]));
            tbin[s] = (unsigned short)bn[i];
        }
    }
    __syncthreads();
    // linear copy out: consecutive lanes -> consecutive addresses within each bin run
    int tot = stotal;
    for (int s = t; s < tot; s += 512) {
        uint2 rec = tile[s];
        int b = tbin[s];
        int pos = gb[b] + (s - binstart[b]);
        if (pos < CAPB) {
            A[(size_t)b * CAPB + pos] = rec;
        } else {                                        // correctness valve (~never)
            int op = atomicAdd(ovcur, 1);
            if (op < OVCAP) {
                int cflat = (b << 10) | (int)(rec.x >> 19);
                ovf[3 * op] = cflat;
                ovf[3 * op + 1] = (int)(rec.x & 0x7FFFFu);
                ovf[3 * op + 2] = (int)rec.y;
            }
        }
    }
}

// ---------------- compact2: per 1024-node bin -> per-node CSR {rflat, ew}; dinv ----------------
__global__ __launch_bounds__(256) void compact2_kernel(const int* __restrict__ gcur,
                                                       const uint2* __restrict__ A,
                                                       const int* __restrict__ ovcur,
                                                       const int* __restrict__ ovf,
                                                       uint2* __restrict__ C,
                                                       int2* __restrict__ nodeoff,
                                                       float* __restrict__ dinv) {
    const int bin = blockIdx.x;
    __shared__ int cnt[BINW];
    __shared__ float wsum[BINW];
    __shared__ int pos[BINW];
    __shared__ int sh[256];
    const int t = threadIdx.x;
    for (int i = t; i < BINW; i += 256) { cnt[i] = 0; wsum[i] = 0.0f; }
    __syncthreads();
    const int len = min(gcur[bin], CAPB);
    const uint2* Ab = A + (size_t)bin * CAPB;
    for (int p = t; p < len; p += 256) {
        uint2 rec = Ab[p];
        atomicAdd(&cnt[rec.x >> 19], 1);
        atomicAdd(&wsum[rec.x >> 19], __uint_as_float(rec.y));
    }
    const int ovn = min(*ovcur, OVCAP);
    for (int i = t; i < ovn; i += 256) {
        int cflat = ovf[3 * i];
        if ((cflat >> 10) == bin) {
            atomicAdd(&cnt[cflat & 1023], 1);
            atomicAdd(&wsum[cflat & 1023], __int_as_float(ovf[3 * i + 2]));
        }
    }
    __syncthreads();
    // scan: thread t owns nodes 4t..4t+3
    int c0 = cnt[4 * t], c1 = cnt[4 * t + 1], c2 = cnt[4 * t + 2], c3 = cnt[4 * t + 3];
    int vsum = c0 + c1 + c2 + c3;
    sh[t] = vsum;
    __syncthreads();
    for (int d = 1; d < 256; d <<= 1) {
        int add = (t >= d) ? sh[t - d] : 0;
        __syncthreads();
        sh[t] += add;
        __syncthreads();
    }
    const int base = bin * CAPB;
    const int lim = base + CAPB;
    int p0 = base + sh[t] - vsum;
    int p1 = p0 + c0, p2 = p1 + c1, p3 = p2 + c2;
    pos[4 * t] = p0; pos[4 * t + 1] = p1; pos[4 * t + 2] = p2; pos[4 * t + 3] = p3;
    int starts[4] = {p0, p1, p2, p3};
    int cs[4] = {c0, c1, c2, c3};
#pragma unroll
    for (int j = 0; j < 4; ++j) {
        int cl = 4 * t + j;
        int node = (bin << 10) + cl;
        if (node < NTOT) {
            nodeoff[node] = make_int2(starts[j], cs[j]);
            float dg = wsum[cl];
            dinv[node] = (dg > 0.0f) ? rsqrtf(dg) : 0.0f;
        }
    }
    __syncthreads();
    for (int p = t; p < len; p += 256) {
        uint2 rec = Ab[p];
        int s = atomicAdd(&pos[rec.x >> 19], 1);
        if (s < lim) C[s] = make_uint2(rec.x & 0x7FFFFu, rec.y);
    }
    for (int i = t; i < ovn; i += 256) {
        int cflat = ovf[3 * i];
        if ((cflat >> 10) == bin) {
            int s = atomicAdd(&pos[cflat & 1023], 1);
            if (s < lim) C[s] = make_uint2((unsigned)ovf[3 * i + 1], (unsigned)ovf[3 * i + 2]);
        }
    }
}

// ---------------- prep: W fp32 [mp][k][n] -> bf16 transposed wT [mp][n][k] ----------------
__global__ __launch_bounds__(256) void prep_w_kernel(const float* __restrict__ W,
                                                     unsigned short* __restrict__ wT) {
    int idx = blockIdx.x * 256 + threadIdx.x;
    if (idx >= NMP * D * D) return;
    int mp = idx >> 12, rem = idx & 4095;
    int k = rem >> 6, n = rem & 63;
    wT[(mp * D + n) * D + k] = f2bf(W[idx]);
}

// ---------------- MFMA GEMM: h'[mp][r] = bf16( (x @ W[mp])[r] * dinv[mp,r] ) ----------------
__global__ __launch_bounds__(256) void gemm_kernel(const float* __restrict__ x,
                                                   const unsigned short* __restrict__ wT,
                                                   const float* __restrict__ dinv,
                                                   unsigned short* __restrict__ h) {
    const int wave = threadIdx.x >> 6;
    const int lane = threadIdx.x & 63;
    const int rowbase = (blockIdx.x * 4 + wave) * 16;
    if (rowbase >= NNODES) return;
    const int m = lane & 15;
    const int q = lane >> 4;
    const float4* xr = (const float4*)(x + (size_t)(rowbase + m) * D);
    bf16x8 a[2];
#pragma unroll
    for (int kc = 0; kc < 2; ++kc) {
        float4 x0 = xr[kc * 8 + q * 2];
        float4 x1 = xr[kc * 8 + q * 2 + 1];
        a[kc][0] = f2bf(x0.x); a[kc][1] = f2bf(x0.y);
        a[kc][2] = f2bf(x0.z); a[kc][3] = f2bf(x0.w);
        a[kc][4] = f2bf(x1.x); a[kc][5] = f2bf(x1.y);
        a[kc][6] = f2bf(x1.z); a[kc][7] = f2bf(x1.w);
    }
#pragma unroll
    for (int mp = 0; mp < NMP; ++mp) {
        float dv[4];
#pragma unroll
        for (int r_ = 0; r_ < 4; ++r_)
            dv[r_] = dinv[mp * NNODES + rowbase + q * 4 + r_];
#pragma unroll
        for (int nt = 0; nt < 4; ++nt) {
            int ncol = nt * 16 + m;
            const bf16x8* bp = (const bf16x8*)(wT + (size_t)(mp * D + ncol) * D);
            bf16x8 b0 = bp[q];
            bf16x8 b1 = bp[4 + q];
            floatx4 acc = {0.f, 0.f, 0.f, 0.f};
            acc = __builtin_amdgcn_mfma_f32_16x16x32_bf16(a[0], b0, acc, 0, 0, 0);
            acc = __builtin_amdgcn_mfma_f32_16x16x32_bf16(a[1], b1, acc, 0, 0, 0);
            unsigned short* hp = h + ((size_t)mp * NNODES + rowbase) * D + ncol;
#pragma unroll
            for (int r_ = 0; r_ < 4; ++r_)
                hp[(q * 4 + r_) * D] = f2bf(acc[r_] * dv[r_]);   // C/D: col=lane&15, row=q*4+r
        }
    }
}

// ---------------- gather: wave per node, register accumulation, 16 pairs in flight ----------------
__global__ __launch_bounds__(256) void gather_kernel(const int2* __restrict__ nodeoff,
                                                     const uint2* __restrict__ dense,
                                                     const unsigned short* __restrict__ h,
                                                     const float* __restrict__ dinv,
                                                     float* __restrict__ out) {
    int w = blockIdx.x * 4 + (threadIdx.x >> 6);
    if (w >= NTOT) return;
    int lane = threadIdx.x & 63;
    int g = lane & 7;    // pair slot within group
    int f = lane >> 3;   // feature chunk (8 bf16 = 16 B)
    int2 off = nodeoff[w];
    int start = off.x, end = off.x + off.y;
    float acc[8] = {0, 0, 0, 0, 0, 0, 0, 0};
    for (int p = start; p < end; p += 16) {
        int i0 = p + g;
        int i1 = p + 8 + g;
        uint2 pr0 = (i0 < end) ? dense[i0] : make_uint2(0u, 0u);   // ew=0 -> no-op
        uint2 pr1 = (i1 < end) ? dense[i1] : make_uint2(0u, 0u);
        uint4 hv0 = ((const uint4*)(h + (size_t)pr0.x * D))[f];
        uint4 hv1 = ((const uint4*)(h + (size_t)pr1.x * D))[f];
        float n0 = __uint_as_float(pr0.y);
        float n1 = __uint_as_float(pr1.y);
        acc[0] += n0 * bf2f_lo(hv0.x); acc[1] += n0 * bf2f_hi(hv0.x);
        acc[2] += n0 * bf2f_lo(hv0.y); acc[3] += n0 * bf2f_hi(hv0.y);
        acc[4] += n0 * bf2f_lo(hv0.z); acc[5] += n0 * bf2f_hi(hv0.z);
        acc[6] += n0 * bf2f_lo(hv0.w); acc[7] += n0 * bf2f_hi(hv0.w);
        acc[0] += n1 * bf2f_lo(hv1.x); acc[1] += n1 * bf2f_hi(hv1.x);
        acc[2] += n1 * bf2f_lo(hv1.y); acc[3] += n1 * bf2f_hi(hv1.y);
        acc[4] += n1 * bf2f_lo(hv1.z); acc[5] += n1 * bf2f_hi(hv1.z);
        acc[6] += n1 * bf2f_lo(hv1.w); acc[7] += n1 * bf2f_hi(hv1.w);
    }
#pragma unroll
    for (int j = 0; j < 8; ++j) {
        acc[j] += __shfl_xor(acc[j], 1);
        acc[j] += __shfl_xor(acc[j], 2);
        acc[j] += __shfl_xor(acc[j], 4);
    }
    int k = lane & 7;   // lane l holds feature (l>>3)*8 + j in acc[j]; wants acc[l&7]
    float b0 = (k & 1) ? acc[1] : acc[0];
    float b1 = (k & 1) ? acc[3] : acc[2];
    float b2 = (k & 1) ? acc[5] : acc[4];
    float b3 = (k & 1) ? acc[7] : acc[6];
    float c0 = (k & 2) ? b1 : b0;
    float c1 = (k & 2) ? b3 : b2;
    float v  = (k & 4) ? c1 : c0;
    out[(size_t)w * D + lane] = fmaxf(v * dinv[w], 0.0f);
}

extern "C" void kernel_launch(void* const* d_in, const int* in_sizes, int n_in,
                              void* d_out, int out_size, void* d_ws, size_t ws_size,
                              hipStream_t stream) {
    const float* x  = (const float*)d_in[0];   // [N, 64]
    const float* W  = (const float*)d_in[1];   // [3, 64, 64]
    const int*   ei = (const int*)d_in[2];     // [3, 2, E]
    const float* ew = (const float*)d_in[3];   // [3, E]
    float* out = (float*)d_out;                // [3, N, 64]

    // layout (bytes). A (25.65 MB) is dead after compact2; h (38.4 MB) overlays it.
    char* ws = (char*)d_ws;
    uint2* A           = (uint2*)(ws + 0);                     // 293*10944*8 = 25,652,736 B
    unsigned short* h  = (unsigned short*)(ws + 0);            // 38,400,000 B (overlays A)
    uint2* C           = (uint2*)(ws + 38400000);              // 25,652,736 B
    int2*  nodeoff     = (int2*)(ws + 64052736);               // 2,400,000 B
    float* dinv        = (float*)(ws + 66452736);              // 1,200,000 B
    unsigned short* wT = (unsigned short*)(ws + 67652736);     // 24,576 B
    int*   gcur        = (int*)(ws + 67677312);                // 1,172 B
    int*   ovcur       = (int*)(ws + 67678484);                // 4 B (adjacent to gcur)
    int*   ovf         = (int*)(ws + 67678488);                // 1,572,864 B -> ends ~69.25 MB

    hipMemsetAsync(gcur, 0, 1176, stream);     // gcur + ovcur

    split_kernel<<<dim3((NEDGES + T1 - 1) / T1, NMP), 512, 0, stream>>>(ei, ew, gcur,
                                                                        ovcur, ovf, A);
    compact2_kernel<<<NBIN, 256, 0, stream>>>(gcur, A, ovcur, ovf, C, nodeoff, dinv);
    prep_w_kernel<<<(NMP * D * D + 255) / 256, 256, 0, stream>>>(W, wT);
    gemm_kernel<<<(NNODES / 16 + 3) / 4, 256, 0, stream>>>(x, wT, dinv, h);
    gather_kernel<<<(NTOT + 3) / 4, 256, 0, stream>>>(nodeoff, C, h, dinv, out);
}

// Round 7
// 291.966 us; speedup vs baseline: 4.7293x; 1.0875x over previous
//
#include <hip/hip_runtime.h>

#define NNODES 100000
#define NMP 3
#define NEDGES 1000000
#define D 64
#define NTOT (NMP * NNODES)          // 300000
#define BINW 1024                    // destination nodes per bin
#define NBIN 293                     // ceil(NTOT / BINW)
#define CAPB 10944                   // slots per bin segment (lambda=10240, +7 sigma)
#define T1 3072                      // edges per split block
#define OVCAP 131072                 // overflow entries (12 B each)

typedef __attribute__((ext_vector_type(8))) short bf16x8;
typedef __attribute__((ext_vector_type(4))) float floatx4;

__device__ __forceinline__ unsigned short f2bf(float f) {
    unsigned u = __float_as_uint(f);
    u = (u + 0x7FFFu + ((u >> 16) & 1u)) >> 16;   // RNE
    return (unsigned short)u;
}
__device__ __forceinline__ float bf2f_lo(unsigned u) { return __uint_as_float(u << 16); }
__device__ __forceinline__ float bf2f_hi(unsigned u) { return __uint_as_float(u & 0xFFFF0000u); }

// ---------------- split: multisplit into 293 bins, direct scatter (no LDS reorder) ----------------
__global__ __launch_bounds__(512) void split_kernel(const int* __restrict__ ei,
                                                    const float* __restrict__ ew,
                                                    int* __restrict__ gcur,
                                                    int* __restrict__ ovcur,
                                                    int* __restrict__ ovf,
                                                    uint2* __restrict__ A) {
    __shared__ int hist[NBIN], cur[NBIN];
    const int t = threadIdx.x;
    const int mp = blockIdx.y;
    const int e0 = blockIdx.x * T1;
    for (int i = t; i < NBIN; i += 512) hist[i] = 0;
    __syncthreads();
    unsigned key[6]; float w[6]; int bn[6];
#pragma unroll
    for (int i = 0; i < 6; ++i) {
        int e = e0 + i * 512 + t;
        bn[i] = -1;
        if (e < NEDGES) {
            int r = ei[(mp * 2 + 0) * NEDGES + e];
            int c = ei[(mp * 2 + 1) * NEDGES + e];
            w[i] = ew[mp * NEDGES + e];
            int cflat = mp * NNODES + c;
            int rflat = mp * NNODES + r;
            int b = cflat >> 10;
            bn[i] = b;
            key[i] = ((unsigned)(cflat & 1023) << 19) | (unsigned)rflat;
            atomicAdd(&hist[b], 1);
        }
    }
    __syncthreads();
    for (int i = t; i < NBIN; i += 512) {
        int v = hist[i];
        cur[i] = v ? atomicAdd(&gcur[i], v) : 0;   // global space reservation -> running cursor
    }
    __syncthreads();
#pragma unroll
    for (int i = 0; i < 6; ++i) {
        if (bn[i] >= 0) {
            int pos = atomicAdd(&cur[bn[i]], 1);
            if (pos < CAPB) {
                A[(size_t)bn[i] * CAPB + pos] = make_uint2(key[i], __float_as_uint(w[i]));
            } else {                               // correctness valve (~never)
                int op = atomicAdd(ovcur, 1);
                if (op < OVCAP) {
                    int cflat = (bn[i] << 10) | (int)(key[i] >> 19);
                    ovf[3 * op] = cflat;
                    ovf[3 * op + 1] = (int)(key[i] & 0x7FFFFu);
                    ovf[3 * op + 2] = __float_as_int(w[i]);
                }
            }
        }
    }
}

// ---------------- compact2: per 1024-node bin -> per-node CSR {rflat, ew}; dinv ----------------
__global__ __launch_bounds__(256) void compact2_kernel(const int* __restrict__ gcur,
                                                       const uint2* __restrict__ A,
                                                       const int* __restrict__ ovcur,
                                                       const int* __restrict__ ovf,
                                                       uint2* __restrict__ C,
                                                       int2* __restrict__ nodeoff,
                                                       float* __restrict__ dinv) {
    const int bin = blockIdx.x;
    __shared__ int cnt[BINW];
    __shared__ float wsum[BINW];
    __shared__ int pos[BINW];
    __shared__ int sh[256];
    const int t = threadIdx.x;
    for (int i = t; i < BINW; i += 256) { cnt[i] = 0; wsum[i] = 0.0f; }
    __syncthreads();
    const int len = min(gcur[bin], CAPB);
    const uint2* Ab = A + (size_t)bin * CAPB;
    for (int p = t; p < len; p += 256) {
        uint2 rec = Ab[p];
        atomicAdd(&cnt[rec.x >> 19], 1);
        atomicAdd(&wsum[rec.x >> 19], __uint_as_float(rec.y));
    }
    const int ovn = min(*ovcur, OVCAP);
    for (int i = t; i < ovn; i += 256) {
        int cflat = ovf[3 * i];
        if ((cflat >> 10) == bin) {
            atomicAdd(&cnt[cflat & 1023], 1);
            atomicAdd(&wsum[cflat & 1023], __int_as_float(ovf[3 * i + 2]));
        }
    }
    __syncthreads();
    // scan: thread t owns nodes 4t..4t+3
    int c0 = cnt[4 * t], c1 = cnt[4 * t + 1], c2 = cnt[4 * t + 2], c3 = cnt[4 * t + 3];
    int vsum = c0 + c1 + c2 + c3;
    sh[t] = vsum;
    __syncthreads();
    for (int d = 1; d < 256; d <<= 1) {
        int add = (t >= d) ? sh[t - d] : 0;
        __syncthreads();
        sh[t] += add;
        __syncthreads();
    }
    const int base = bin * CAPB;
    const int lim = base + CAPB;
    int p0 = base + sh[t] - vsum;
    int p1 = p0 + c0, p2 = p1 + c1, p3 = p2 + c2;
    pos[4 * t] = p0; pos[4 * t + 1] = p1; pos[4 * t + 2] = p2; pos[4 * t + 3] = p3;
    int starts[4] = {p0, p1, p2, p3};
    int cs[4] = {c0, c1, c2, c3};
#pragma unroll
    for (int j = 0; j < 4; ++j) {
        int cl = 4 * t + j;
        int node = (bin << 10) + cl;
        if (node < NTOT) {
            nodeoff[node] = make_int2(starts[j], cs[j]);
            float dg = wsum[cl];
            dinv[node] = (dg > 0.0f) ? rsqrtf(dg) : 0.0f;
        }
    }
    __syncthreads();
    for (int p = t; p < len; p += 256) {
        uint2 rec = Ab[p];
        int s = atomicAdd(&pos[rec.x >> 19], 1);
        if (s < lim) C[s] = make_uint2(rec.x & 0x7FFFFu, rec.y);
    }
    for (int i = t; i < ovn; i += 256) {
        int cflat = ovf[3 * i];
        if ((cflat >> 10) == bin) {
            int s = atomicAdd(&pos[cflat & 1023], 1);
            if (s < lim) C[s] = make_uint2((unsigned)ovf[3 * i + 1], (unsigned)ovf[3 * i + 2]);
        }
    }
}

// ---------------- prep: W fp32 [mp][k][n] -> bf16 transposed wT [mp][n][k] ----------------
__global__ __launch_bounds__(256) void prep_w_kernel(const float* __restrict__ W,
                                                     unsigned short* __restrict__ wT) {
    int idx = blockIdx.x * 256 + threadIdx.x;
    if (idx >= NMP * D * D) return;
    int mp = idx >> 12, rem = idx & 4095;
    int k = rem >> 6, n = rem & 63;
    wT[(mp * D + n) * D + k] = f2bf(W[idx]);
}

// ---------------- MFMA GEMM (operand-swapped): lane's 4 accs are contiguous in h ----------------
// D' = wTfrag(A) @ xfrag(B): D'[n][r] with col=lane&15 -> x-row, reg j -> out-col q*4+j.
__global__ __launch_bounds__(256) void gemm_kernel(const float* __restrict__ x,
                                                   const unsigned short* __restrict__ wT,
                                                   const float* __restrict__ dinv,
                                                   unsigned short* __restrict__ h) {
    const int wave = threadIdx.x >> 6;
    const int lane = threadIdx.x & 63;
    const int rowbase = (blockIdx.x * 4 + wave) * 16;
    if (rowbase >= NNODES) return;
    const int m = lane & 15;
    const int q = lane >> 4;
    const float4* xr = (const float4*)(x + (size_t)(rowbase + m) * D);
    bf16x8 a[2];
#pragma unroll
    for (int kc = 0; kc < 2; ++kc) {
        float4 x0 = xr[kc * 8 + q * 2];
        float4 x1 = xr[kc * 8 + q * 2 + 1];
        a[kc][0] = f2bf(x0.x); a[kc][1] = f2bf(x0.y);
        a[kc][2] = f2bf(x0.z); a[kc][3] = f2bf(x0.w);
        a[kc][4] = f2bf(x1.x); a[kc][5] = f2bf(x1.y);
        a[kc][6] = f2bf(x1.z); a[kc][7] = f2bf(x1.w);
    }
#pragma unroll
    for (int mp = 0; mp < NMP; ++mp) {
        float dv = dinv[mp * NNODES + rowbase + m];   // per x-row scale
#pragma unroll
        for (int nt = 0; nt < 4; ++nt) {
            const bf16x8* bp = (const bf16x8*)(wT + (size_t)(mp * D + nt * 16 + m) * D);
            bf16x8 b0 = bp[q];       // k = q*8 .. +7
            bf16x8 b1 = bp[4 + q];   // k = 32 + q*8 .. +7
            floatx4 acc = {0.f, 0.f, 0.f, 0.f};
            acc = __builtin_amdgcn_mfma_f32_16x16x32_bf16(b0, a[0], acc, 0, 0, 0);
            acc = __builtin_amdgcn_mfma_f32_16x16x32_bf16(b1, a[1], acc, 0, 0, 0);
            unsigned v0 = (unsigned)f2bf(acc[0] * dv) | ((unsigned)f2bf(acc[1] * dv) << 16);
            unsigned v1 = (unsigned)f2bf(acc[2] * dv) | ((unsigned)f2bf(acc[3] * dv) << 16);
            *(uint2*)(h + ((size_t)mp * NNODES + rowbase + m) * D + nt * 16 + q * 4) =
                make_uint2(v0, v1);
        }
    }
}

// ---------------- gather: 4 nodes/wave (16 lanes each: 2 pair-slots x 8 feat-chunks) ----------------
__global__ __launch_bounds__(256) void gather_kernel(const int2* __restrict__ nodeoff,
                                                     const uint2* __restrict__ dense,
                                                     const unsigned short* __restrict__ h,
                                                     const float* __restrict__ dinv,
                                                     float* __restrict__ out) {
    const int tid = threadIdx.x;
    const int wave = tid >> 6, lane = tid & 63;
    const int sub = lane >> 4;     // node within wave
    const int g = (lane >> 3) & 1; // pair slot
    const int f = lane & 7;        // feature chunk (8 bf16 = 16 B)
    const int w = blockIdx.x * 16 + wave * 4 + sub;   // NTOT = 16*18750
    int2 off = nodeoff[w];
    int start = off.x, end = off.x + off.y;
    float acc[8] = {0, 0, 0, 0, 0, 0, 0, 0};
    for (int p = start; p < end; p += 2) {
        int i = p + g;
        uint2 pr = dense[min(i, end - 1)];
        float n0 = (i < end) ? __uint_as_float(pr.y) : 0.0f;
        uint4 hv = ((const uint4*)(h + (size_t)pr.x * D))[f];
        acc[0] += n0 * bf2f_lo(hv.x); acc[1] += n0 * bf2f_hi(hv.x);
        acc[2] += n0 * bf2f_lo(hv.y); acc[3] += n0 * bf2f_hi(hv.y);
        acc[4] += n0 * bf2f_lo(hv.z); acc[5] += n0 * bf2f_hi(hv.z);
        acc[6] += n0 * bf2f_lo(hv.w); acc[7] += n0 * bf2f_hi(hv.w);
    }
#pragma unroll
    for (int j = 0; j < 8; ++j) acc[j] += __shfl_xor(acc[j], 8);   // reduce across g
    float dv = dinv[w];
    float4 o = g ? make_float4(acc[4], acc[5], acc[6], acc[7])
                 : make_float4(acc[0], acc[1], acc[2], acc[3]);
    o.x = fmaxf(o.x * dv, 0.0f);
    o.y = fmaxf(o.y * dv, 0.0f);
    o.z = fmaxf(o.z * dv, 0.0f);
    o.w = fmaxf(o.w * dv, 0.0f);
    ((float4*)(out + (size_t)w * D))[f * 2 + g] = o;   // 256 B contiguous per node
}

extern "C" void kernel_launch(void* const* d_in, const int* in_sizes, int n_in,
                              void* d_out, int out_size, void* d_ws, size_t ws_size,
                              hipStream_t stream) {
    const float* x  = (const float*)d_in[0];   // [N, 64]
    const float* W  = (const float*)d_in[1];   // [3, 64, 64]
    const int*   ei = (const int*)d_in[2];     // [3, 2, E]
    const float* ew = (const float*)d_in[3];   // [3, E]
    float* out = (float*)d_out;                // [3, N, 64]

    // layout (bytes). A (25.65 MB) is dead after compact2; h (38.4 MB) overlays it.
    char* ws = (char*)d_ws;
    uint2* A           = (uint2*)(ws + 0);                     // 293*10944*8 = 25,652,736 B
    unsigned short* h  = (unsigned short*)(ws + 0);            // 38,400,000 B (overlays A)
    uint2* C           = (uint2*)(ws + 38400000);              // 25,652,736 B
    int2*  nodeoff     = (int2*)(ws + 64052736);               // 2,400,000 B
    float* dinv        = (float*)(ws + 66452736);              // 1,200,000 B
    unsigned short* wT = (unsigned short*)(ws + 67652736);     // 24,576 B
    int*   gcur        = (int*)(ws + 67677312);                // 1,172 B
    int*   ovcur       = (int*)(ws + 67678484);                // 4 B (adjacent to gcur)
    int*   ovf         = (int*)(ws + 67678488);                // 1,572,864 B -> ends ~69.25 MB

    hipMemsetAsync(gcur, 0, 1176, stream);     // gcur + ovcur

    split_kernel<<<dim3((NEDGES + T1 - 1) / T1, NMP), 512, 0, stream>>>(ei, ew, gcur,
                                                                        ovcur, ovf, A);
    compact2_kernel<<<NBIN, 256, 0, stream>>>(gcur, A, ovcur, ovf, C, nodeoff, dinv);
    prep_w_kernel<<<(NMP * D * D + 255) / 256, 256, 0, stream>>>(W, wT);
    gemm_kernel<<<(NNODES / 16 + 3) / 4, 256, 0, stream>>>(x, wT, dinv, h);
    gather_kernel<<<NTOT / 16, 256, 0, stream>>>(nodeoff, C, h, dinv, out);
}